// Round 1
// baseline (220.285 us; speedup 1.0000x reference)
//
#include <hip/hip_runtime.h>
#include <stdint.h>

#pragma clang fp contract(off)

#define NMS_B 8
#define NMS_N 4096
#define NMS_NW 64       // 64-bit words per suppression row
#define ROIS 256

typedef unsigned long long u64;
typedef unsigned int u32;

__device__ inline u64 shfl64(u64 v, int src) {
    int lo = __shfl((int)(u32)(v & 0xffffffffULL), src);
    int hi = __shfl((int)(u32)(v >> 32), src);
    return ((u64)(u32)hi << 32) | (u32)lo;
}

// ---------------------------------------------------------------------------
// K1: per-batch stable descending sort by score (bitonic, 64-bit composite
// key = (~score_bits)<<32 | index), then compute corners exactly as the
// reference (ws = floor(w/2) etc.) and write SoA corner arrays + sorted idx.
// ---------------------------------------------------------------------------
__global__ __launch_bounds__(1024) void nms_sort(
        const float* __restrict__ in, u32* __restrict__ sortedIdx,
        float* __restrict__ cx1, float* __restrict__ cy1,
        float* __restrict__ cx2, float* __restrict__ cy2,
        float* __restrict__ car) {
    __shared__ u64 keys[NMS_N];               // 32 KB
    const int b = blockIdx.x, tid = threadIdx.x;

    for (int p = tid; p < NMS_N; p += 1024) {
        float s = in[((size_t)b * NMS_N + p) * 5 + 0];
        u32 sb = __float_as_uint(s);          // scores in [0,1): monotone bits
        keys[p] = ((u64)(~sb) << 32) | (u32)p;
    }
    __syncthreads();

    // ascending bitonic sort of 4096 keys: descending score, ties -> low idx
    for (int k = 2; k <= NMS_N; k <<= 1) {
        for (int j = k >> 1; j > 0; j >>= 1) {
            for (int e = tid; e < NMS_N; e += 1024) {
                int p = e ^ j;
                if (p > e) {
                    u64 a = keys[e], c = keys[p];
                    bool up = ((e & k) == 0);
                    if ((a > c) == up) { keys[e] = c; keys[p] = a; }
                }
            }
            __syncthreads();
        }
    }

    for (int p = tid; p < NMS_N; p += 1024) {
        u32 orig = (u32)keys[p];
        const float* bp = in + ((size_t)b * NMS_N + orig) * 5;
        float x = bp[1], y = bp[2], w = bp[3], h = bp[4];
        float ws_ = floorf(w * 0.5f);
        float hs_ = floorf(h * 0.5f);
        float X1 = x - ws_, Y1 = y - hs_, X2 = x + ws_, Y2 = y + hs_;
        size_t g = (size_t)b * NMS_N + p;
        sortedIdx[g] = orig;
        cx1[g] = X1; cy1[g] = Y1; cx2[g] = X2; cy2[g] = Y2;
        car[g] = (X2 - X1) * (Y2 - Y1);
    }
}

// ---------------------------------------------------------------------------
// K2: pairwise suppression bitmask. mask[b][row][w] bit t = IoU(row, 64w+t)
// > 0.5 (test: inter > 0.5*union, exact-equivalent to ref up to half-ulp).
// Tiles / words fully below the diagonal are left unwritten: their bits only
// cover j < i, which the forward scan never re-reads.
// ---------------------------------------------------------------------------
__global__ __launch_bounds__(256) void nms_mask(
        const float* __restrict__ cx1, const float* __restrict__ cy1,
        const float* __restrict__ cx2, const float* __restrict__ cy2,
        const float* __restrict__ car, u64* __restrict__ mask) {
    const int cb = blockIdx.x, rb = blockIdx.y, b = blockIdx.z, tid = threadIdx.x;
    if ((cb + 1) * 1024 <= rb * 256) return;   // tile fully below diagonal

    __shared__ float4 lc[1024];                // col corners, 16 KB
    __shared__ float  la[1024];                // col areas,    4 KB
    const size_t base = (size_t)b * NMS_N;
    const int colbase = cb * 1024;

    for (int c = tid; c < 1024; c += 256) {
        size_t g = base + colbase + c;
        lc[c] = make_float4(cx1[g], cy1[g], cx2[g], cy2[g]);
        la[c] = car[g];
    }
    __syncthreads();

    const int row = rb * 256 + tid;
    size_t g = base + row;
    float rx1 = cx1[g], ry1 = cy1[g], rx2 = cx2[g], ry2 = cy2[g], ra = car[g];
    u64* out = mask + ((size_t)(b * NMS_N + row)) * NMS_NW + cb * 16;

    for (int wdi = 0; wdi < 16; ++wdi) {
        if (colbase + (wdi + 1) * 64 <= row) continue;  // word fully below diag
        u64 bits = 0;
        #pragma unroll 16
        for (int t = 0; t < 64; ++t) {
            float4 cc = lc[wdi * 64 + t];
            float ca = la[wdi * 64 + t];
            float ix1 = fmaxf(rx1, cc.x), iy1 = fmaxf(ry1, cc.y);
            float ix2 = fminf(rx2, cc.z), iy2 = fminf(ry2, cc.w);
            float iw = fmaxf(ix2 - ix1, 0.0f), ih = fmaxf(iy2 - iy1, 0.0f);
            float inter = iw * ih;
            float uni = (ra + ca) - inter;
            bits |= ((u64)(inter > 0.5f * uni)) << t;
        }
        out[wdi] = bits;
    }
}

// ---------------------------------------------------------------------------
// K3: one wave per batch. Serial greedy scan over the bitmask: suppressed is
// 4096 bits held as one u64 per lane; row i is OR'd in when i is kept.
// Rows prefetched 16 ahead to hide L2 latency. Early exit at 256 keeps.
// Then gather original regs for the kept boxes.
// ---------------------------------------------------------------------------
__global__ __launch_bounds__(64) void nms_scan(
        const float* __restrict__ in, const u64* __restrict__ mask,
        const u32* __restrict__ sortedIdx, float* __restrict__ outp) {
    const int b = blockIdx.x, lane = threadIdx.x;
    const u64* M = mask + (size_t)b * NMS_N * NMS_NW;

    __shared__ int kept[ROIS];
    for (int r = lane; r < ROIS; r += 64) kept[r] = 0;  // safety fallback

    u64 supp = 0;
    int count = 0;
    u64 cur[16], nxt[16];
    #pragma unroll
    for (int k = 0; k < 16; ++k) cur[k] = M[(size_t)k * NMS_NW + lane];

    for (int base = 0; base < NMS_N; base += 16) {
        int nb = base + 16;
        #pragma unroll
        for (int k = 0; k < 16; ++k)
            nxt[k] = (nb + k < NMS_N) ? M[(size_t)(nb + k) * NMS_NW + lane] : 0ULL;
        #pragma unroll
        for (int k = 0; k < 16; ++k) {
            int i = base + k;
            u64 wv = shfl64(supp, i >> 6);
            if (!((wv >> (i & 63)) & 1ULL)) {
                if (count < ROIS) {
                    if (lane == 0) kept[count] = i;
                    supp |= cur[k];
                }
                count++;
            }
        }
        if (count >= ROIS) break;
        #pragma unroll
        for (int k = 0; k < 16; ++k) cur[k] = nxt[k];
    }
    __syncthreads();

    for (int r = lane; r < ROIS; r += 64) {
        int pos = kept[r];
        int orig = (int)sortedIdx[(size_t)b * NMS_N + pos];
        const float* bp = in + ((size_t)b * NMS_N + orig) * 5;
        float4 o = make_float4(bp[1], bp[2], bp[3], bp[4]);
        ((float4*)outp)[(size_t)b * ROIS + r] = o;
    }
}

extern "C" void kernel_launch(void* const* d_in, const int* in_sizes, int n_in,
                              void* d_out, int out_size, void* d_ws, size_t ws_size,
                              hipStream_t stream) {
    const float* in = (const float*)d_in[0];
    float* out = (float*)d_out;
    char* ws = (char*)d_ws;

    u64* mask = (u64*)ws;                                         // 16 MB
    size_t off = (size_t)NMS_B * NMS_N * NMS_NW * sizeof(u64);
    u32* sortedIdx = (u32*)(ws + off); off += (size_t)NMS_B * NMS_N * 4;
    float* cx1 = (float*)(ws + off);   off += (size_t)NMS_B * NMS_N * 4;
    float* cy1 = (float*)(ws + off);   off += (size_t)NMS_B * NMS_N * 4;
    float* cx2 = (float*)(ws + off);   off += (size_t)NMS_B * NMS_N * 4;
    float* cy2 = (float*)(ws + off);   off += (size_t)NMS_B * NMS_N * 4;
    float* car = (float*)(ws + off);   off += (size_t)NMS_B * NMS_N * 4;

    nms_sort<<<NMS_B, 1024, 0, stream>>>(in, sortedIdx, cx1, cy1, cx2, cy2, car);
    nms_mask<<<dim3(4, 16, NMS_B), 256, 0, stream>>>(cx1, cy1, cx2, cy2, car, mask);
    nms_scan<<<NMS_B, 64, 0, stream>>>(in, mask, sortedIdx, out);
}

// Round 2
// 186.379 us; speedup vs baseline: 1.1819x; 1.1819x over previous
//
#include <hip/hip_runtime.h>
#include <stdint.h>

#pragma clang fp contract(off)

#define NMS_B 8
#define NMS_N 4096
#define NMS_NW 64       // 64-bit words per suppression row
#define ROIS 256

typedef unsigned long long u64;
typedef unsigned int u32;

__device__ __forceinline__ float rdlane_f(float v, int l) {
    return __uint_as_float((u32)__builtin_amdgcn_readlane((int)__float_as_uint(v), l));
}
__device__ __forceinline__ u64 rdlane_u64(u64 v, int l) {
    u32 lo = (u32)__builtin_amdgcn_readlane((int)(u32)v, l);
    u32 hi = (u32)__builtin_amdgcn_readlane((int)(u32)(v >> 32), l);
    return ((u64)hi << 32) | lo;
}
__device__ __forceinline__ int lds_slot(int e) { return e + (e >> 2); }  // 4-way max bank aliasing

// ---------------------------------------------------------------------------
// K1: per-batch stable descending sort by score. Register-blocked bitonic:
// each of 1024 threads owns 4 consecutive elements (key = (~score)<<32|idx).
// j<=2 in-register, j=4..128 via shfl_xor within the wave (wave owns 256
// consecutive elems), j>=256 via LDS compare-swap chains (10 phases total).
// Epilogue writes sorted idx + corners (exactly floor(w/2) per reference)
// + HALF-areas (exact: areas are small even integers).
// ---------------------------------------------------------------------------
__global__ __launch_bounds__(1024) void nms_sort(
        const float* __restrict__ in, u32* __restrict__ sortedIdx,
        float4* __restrict__ crn, float* __restrict__ ha) {
    __shared__ u64 sm[5120];                  // slot(4095)=5118 -> 41 KB
    const int b = blockIdx.x, t = threadIdx.x;
    u64 key[4];

    #pragma unroll
    for (int r = 0; r < 4; ++r) {
        int e = 4 * t + r;
        float s = in[((size_t)b * NMS_N + e) * 5 + 0];
        key[r] = ((u64)(~__float_as_uint(s)) << 32) | (u32)e;
    }

    for (int k = 2; k <= NMS_N; k <<= 1) {
        int j = k >> 1;
        if (j >= 256) {                        // LDS chain for big strides
            #pragma unroll
            for (int r = 0; r < 4; ++r) sm[lds_slot(4 * t + r)] = key[r];
            __syncthreads();
            for (; j >= 256; j >>= 1) {
                for (int e = t; e < NMS_N; e += 1024) {
                    int p = e ^ j;
                    if (p > e) {
                        u64 a = sm[lds_slot(e)], c = sm[lds_slot(p)];
                        bool up = ((e & k) == 0);
                        if ((a > c) == up) { sm[lds_slot(e)] = c; sm[lds_slot(p)] = a; }
                    }
                }
                __syncthreads();
            }
            #pragma unroll
            for (int r = 0; r < 4; ++r) key[r] = sm[lds_slot(4 * t + r)];
            // only own-slot accesses from here until next chain's own-slot
            // writes -> no extra barrier needed
        }
        for (; j >= 4; j >>= 1) {              // cross-thread via shfl_xor
            int d = j >> 2;
            #pragma unroll
            for (int r = 0; r < 4; ++r) {
                int e = 4 * t + r;
                u64 mine = key[r];
                u64 part = __shfl_xor(mine, d, 64);
                bool up = ((e & k) == 0);
                bool lower = ((e & j) == 0);
                u64 mn = (mine < part) ? mine : part;
                u64 mx = (mine < part) ? part : mine;
                key[r] = (up == lower) ? mn : mx;
            }
        }
        for (; j >= 1; j >>= 1) {              // j in {2,1}: in-thread
            #pragma unroll
            for (int r = 0; r < 4; ++r) {
                int pr = r | j;
                if (((r & j) == 0) && pr < 4) {
                    int e = 4 * t + r;
                    bool up = ((e & k) == 0);
                    u64 a = key[r], c = key[pr];
                    if ((a > c) == up) { key[r] = c; key[pr] = a; }
                }
            }
        }
    }

    #pragma unroll
    for (int r = 0; r < 4; ++r) {
        int e = 4 * t + r;
        u32 orig = (u32)key[r];
        const float* bp = in + ((size_t)b * NMS_N + orig) * 5;
        float x = bp[1], y = bp[2], w = bp[3], h = bp[4];
        float ws_ = floorf(w * 0.5f);
        float hs_ = floorf(h * 0.5f);
        float X1 = x - ws_, Y1 = y - hs_, X2 = x + ws_, Y2 = y + hs_;
        size_t g = (size_t)b * NMS_N + e;
        sortedIdx[g] = orig;
        crn[g] = make_float4(X1, Y1, X2, Y2);
        ha[g] = 0.5f * ((X2 - X1) * (Y2 - Y1));   // exact: area is a small int
    }
}

// ---------------------------------------------------------------------------
// K2: suppression bitmask, ballot orientation. Each lane owns TWO columns
// (regs, loaded once); rows are broadcast via v_readlane; v_cmp/__ballot
// emits the 64-bit mask word directly. No LDS in the inner loop.
// Rows >= 128*(wp+1) never read these words (all their bits are j<i), so
// they're skipped; poison left there is harmless to the scan.
// Test inter > (hra+hca) - 0.5*inter  ==  inter > 0.5*union bit-exactly
// (areas are exact integers; halving exact; fma rounds once like the sub).
// ---------------------------------------------------------------------------
__global__ __launch_bounds__(256) void nms_mask(
        const float4* __restrict__ crn, const float* __restrict__ ha,
        u64* __restrict__ mask) {
    const int wp = blockIdx.x;                 // 0..31 : cols [wp*128, wp*128+128)
    const int chunk = blockIdx.y;              // 0..7  : rows [chunk*512, +512)
    const int b = blockIdx.z;
    const int wave = threadIdx.x >> 6, lane = threadIdx.x & 63;
    const int rowbase = chunk * 512 + wave * 128;
    const int rowend = 128 * (wp + 1);         // rows needing these words
    if (rowbase >= rowend) return;

    const size_t base = (size_t)b * NMS_N;
    const int c0 = wp * 128 + lane;
    float4 c0c = crn[base + c0];
    float4 c1c = crn[base + c0 + 64];
    float h0 = ha[base + c0];
    float h1 = ha[base + c0 + 64];

    for (int rb = rowbase; rb < rowbase + 128; rb += 64) {
        float4 rc = crn[base + rb + lane];
        float rh = ha[base + rb + lane];
        u64 w0 = 0, w1 = 0;
        #pragma unroll 4
        for (int r = 0; r < 64; ++r) {
            float rx1 = rdlane_f(rc.x, r), ry1 = rdlane_f(rc.y, r);
            float rx2 = rdlane_f(rc.z, r), ry2 = rdlane_f(rc.w, r);
            float rha = rdlane_f(rh, r);

            float iw0 = fmaxf(fminf(rx2, c0c.z) - fmaxf(rx1, c0c.x), 0.0f);
            float ih0 = fmaxf(fminf(ry2, c0c.w) - fmaxf(ry1, c0c.y), 0.0f);
            float in0 = iw0 * ih0;
            bool p0 = in0 > fmaf(-0.5f, in0, rha + h0);

            float iw1 = fmaxf(fminf(rx2, c1c.z) - fmaxf(rx1, c1c.x), 0.0f);
            float ih1 = fmaxf(fminf(ry2, c1c.w) - fmaxf(ry1, c1c.y), 0.0f);
            float in1 = iw1 * ih1;
            bool p1 = in1 > fmaf(-0.5f, in1, rha + h1);

            u64 b0 = __ballot(p0);
            u64 b1 = __ballot(p1);
            if (lane == r) { w0 = b0; w1 = b1; }
        }
        ulonglong2 v; v.x = w0; v.y = w1;
        *(ulonglong2*)&mask[(base + rb + lane) * NMS_NW + wp * 2] = v;
    }
}

// ---------------------------------------------------------------------------
// K3: one wave per batch, serial greedy scan. Suppression state: one u64 per
// lane (lane = 64-row window). The CURRENT window's word is broadcast to a
// scalar reg (readlane) so suppressed rows cost a few scalar ops; kept rows
// OR their (prefetched, double-buffered) mask row into supp. Early exit at
// 256 keeps.
// ---------------------------------------------------------------------------
__global__ __launch_bounds__(64, 1) void nms_scan(
        const float* __restrict__ in, const u64* __restrict__ mask,
        const u32* __restrict__ sortedIdx, float* __restrict__ outp) {
    const int b = blockIdx.x, lane = threadIdx.x;
    const u64* M = mask + (size_t)b * NMS_N * NMS_NW;

    __shared__ int kept[ROIS];
    for (int r = lane; r < ROIS; r += 64) kept[r] = 0;   // safety fallback

    u64 supp = 0;
    int count = 0;
    u64 bufA[64], bufB[64];

    #pragma unroll
    for (int r = 0; r < 64; ++r) bufA[r] = M[(size_t)r * NMS_NW + lane];

#define PROCESS(BUF, W)                                                    \
    {                                                                      \
        u64 curwin = rdlane_u64(supp, (W));                                \
        _Pragma("unroll")                                                  \
        for (int r = 0; r < 64; ++r) {                                     \
            if (count < ROIS && !((curwin >> r) & 1ULL)) {                 \
                if (lane == 0) kept[count] = (W) * 64 + r;                 \
                supp |= BUF[r];                                            \
                curwin |= rdlane_u64(BUF[r], (W));                         \
                ++count;                                                   \
            }                                                              \
        }                                                                  \
    }

    for (int w = 0; w < 64 && count < ROIS; w += 2) {
        // prefetch window w+1 into B
        #pragma unroll
        for (int r = 0; r < 64; ++r)
            bufB[r] = M[(size_t)((w + 1) * 64 + r) * NMS_NW + lane];
        PROCESS(bufA, w);
        if (count >= ROIS) break;
        // prefetch window w+2 into A
        if (w + 2 < 64) {
            #pragma unroll
            for (int r = 0; r < 64; ++r)
                bufA[r] = M[(size_t)((w + 2) * 64 + r) * NMS_NW + lane];
        }
        PROCESS(bufB, w + 1);
    }
#undef PROCESS

    __syncthreads();
    for (int r = lane; r < ROIS; r += 64) {
        int pos = kept[r];
        int orig = (int)sortedIdx[(size_t)b * NMS_N + pos];
        const float* bp = in + ((size_t)b * NMS_N + orig) * 5;
        float4 o = make_float4(bp[1], bp[2], bp[3], bp[4]);
        ((float4*)outp)[(size_t)b * ROIS + r] = o;
    }
}

extern "C" void kernel_launch(void* const* d_in, const int* in_sizes, int n_in,
                              void* d_out, int out_size, void* d_ws, size_t ws_size,
                              hipStream_t stream) {
    const float* in = (const float*)d_in[0];
    float* out = (float*)d_out;
    char* ws = (char*)d_ws;

    u64* mask = (u64*)ws;                                          // 16 MB
    size_t off = (size_t)NMS_B * NMS_N * NMS_NW * sizeof(u64);
    u32* sortedIdx = (u32*)(ws + off); off += (size_t)NMS_B * NMS_N * 4;
    float4* crn = (float4*)(ws + off); off += (size_t)NMS_B * NMS_N * 16;
    float* ha = (float*)(ws + off);    off += (size_t)NMS_B * NMS_N * 4;

    nms_sort<<<NMS_B, 1024, 0, stream>>>(in, sortedIdx, crn, ha);
    nms_mask<<<dim3(32, 8, NMS_B), 256, 0, stream>>>(crn, ha, mask);
    nms_scan<<<NMS_B, 64, 0, stream>>>(in, mask, sortedIdx, out);
}

// Round 3
// 153.773 us; speedup vs baseline: 1.4325x; 1.2120x over previous
//
#include <hip/hip_runtime.h>
#include <stdint.h>

#pragma clang fp contract(off)

#define NMS_B 8
#define NMS_N 4096
#define NMS_NW 64       // 64-bit words per suppression row
#define ROIS 256

typedef unsigned long long u64;
typedef unsigned int u32;

__device__ __forceinline__ u64 rdlane_u64(u64 v, int l) {
    u32 lo = (u32)__builtin_amdgcn_readlane((int)(u32)v, l);
    u32 hi = (u32)__builtin_amdgcn_readlane((int)(u32)(v >> 32), l);
    return ((u64)hi << 32) | lo;
}
__device__ __forceinline__ int lds_slot(int e) { return e + (e >> 2); }  // 4-way max bank aliasing

// ---------------------------------------------------------------------------
// K1: per-batch stable descending sort by score. Register-blocked bitonic:
// each of 1024 threads owns 4 consecutive elements (key = (~score)<<32|idx).
// j<=2 in-register, j=4..128 via shfl_xor within the wave, j>=256 via LDS
// compare-swap chains. Epilogue writes sorted idx + corners (floor(w/2),
// exactly per reference) + HALF-areas (exact: areas are small even ints).
// ---------------------------------------------------------------------------
__global__ __launch_bounds__(1024) void nms_sort(
        const float* __restrict__ in, u32* __restrict__ sortedIdx,
        float4* __restrict__ crn, float* __restrict__ ha) {
    __shared__ u64 sm[5120];                  // slot(4095)=5118 -> 41 KB
    const int b = blockIdx.x, t = threadIdx.x;
    u64 key[4];

    #pragma unroll
    for (int r = 0; r < 4; ++r) {
        int e = 4 * t + r;
        float s = in[((size_t)b * NMS_N + e) * 5 + 0];
        key[r] = ((u64)(~__float_as_uint(s)) << 32) | (u32)e;
    }

    for (int k = 2; k <= NMS_N; k <<= 1) {
        int j = k >> 1;
        if (j >= 256) {                        // LDS chain for big strides
            #pragma unroll
            for (int r = 0; r < 4; ++r) sm[lds_slot(4 * t + r)] = key[r];
            __syncthreads();
            for (; j >= 256; j >>= 1) {
                for (int e = t; e < NMS_N; e += 1024) {
                    int p = e ^ j;
                    if (p > e) {
                        u64 a = sm[lds_slot(e)], c = sm[lds_slot(p)];
                        bool up = ((e & k) == 0);
                        if ((a > c) == up) { sm[lds_slot(e)] = c; sm[lds_slot(p)] = a; }
                    }
                }
                __syncthreads();
            }
            #pragma unroll
            for (int r = 0; r < 4; ++r) key[r] = sm[lds_slot(4 * t + r)];
        }
        for (; j >= 4; j >>= 1) {              // cross-thread via shfl_xor
            int d = j >> 2;
            #pragma unroll
            for (int r = 0; r < 4; ++r) {
                int e = 4 * t + r;
                u64 mine = key[r];
                u64 part = __shfl_xor(mine, d, 64);
                bool up = ((e & k) == 0);
                bool lower = ((e & j) == 0);
                u64 mn = (mine < part) ? mine : part;
                u64 mx = (mine < part) ? part : mine;
                key[r] = (up == lower) ? mn : mx;
            }
        }
        for (; j >= 1; j >>= 1) {              // j in {2,1}: in-thread
            #pragma unroll
            for (int r = 0; r < 4; ++r) {
                int pr = r | j;
                if (((r & j) == 0) && pr < 4) {
                    int e = 4 * t + r;
                    bool up = ((e & k) == 0);
                    u64 a = key[r], c = key[pr];
                    if ((a > c) == up) { key[r] = c; key[pr] = a; }
                }
            }
        }
    }

    #pragma unroll
    for (int r = 0; r < 4; ++r) {
        int e = 4 * t + r;
        u32 orig = (u32)key[r];
        const float* bp = in + ((size_t)b * NMS_N + orig) * 5;
        float x = bp[1], y = bp[2], w = bp[3], h = bp[4];
        float ws_ = floorf(w * 0.5f);
        float hs_ = floorf(h * 0.5f);
        float X1 = x - ws_, Y1 = y - hs_, X2 = x + ws_, Y2 = y + hs_;
        size_t g = (size_t)b * NMS_N + e;
        sortedIdx[g] = orig;
        crn[g] = make_float4(X1, Y1, X2, Y2);
        ha[g] = 0.5f * ((X2 - X1) * (Y2 - Y1));   // exact: area is a small int
    }
}

// ---------------------------------------------------------------------------
// K2: suppression bitmask, ballot orientation, EQUAL-WORK trapezoid grid.
// One wave = one unit = 64 rows x 128 cols. Units per word-pair wp:
// 2*(wp+1)  (rows 0..128*(wp+1) need these words); cumulative = wp*(wp+1).
// 1056 units/batch, 4 waves/block -> grid (264, NMS_B). No early exits.
// Each lane owns TWO columns (regs); rows are wave-uniform scalar loads
// (s_load via readfirstlane'd base); v_cmp/__ballot emits the mask word.
// Test inter > (hra+hca) - 0.5*inter  ==  inter/union > 0.5 bit-exactly
// (areas are exact small ints; halving exact). Below-diagonal words are
// never written NOR read by the scan.
// ---------------------------------------------------------------------------
__global__ __launch_bounds__(256) void nms_mask(
        const float4* __restrict__ crn, const float* __restrict__ ha,
        u64* __restrict__ mask) {
    const int b = blockIdx.y;
    const int u = blockIdx.x * 4 + (threadIdx.x >> 6);   // unit id, 0..1055
    const int lane = threadIdx.x & 63;

    // triangular decode: wp s.t. wp*(wp+1) <= u < (wp+1)*(wp+2)
    int wp = (int)sqrtf((float)u);
    while (wp * (wp + 1) > u) --wp;
    while ((wp + 1) * (wp + 2) <= u) ++wp;
    const int rowblk = u - wp * (wp + 1);                // 0..2*wp+1

    const size_t base = (size_t)b * NMS_N;
    const int c0 = wp * 128 + lane;
    float4 c0c = crn[base + c0];
    float4 c1c = crn[base + c0 + 64];
    float h0 = ha[base + c0];
    float h1 = ha[base + c0 + 64];

    const int rowbase = __builtin_amdgcn_readfirstlane(rowblk * 64);
    const float4* rowc = crn + base + rowbase;
    const float* rowh = ha + base + rowbase;

    u64 w0 = 0, w1 = 0;
    for (int rg = 0; rg < 64; rg += 8) {
        float fx1[8], fy1[8], fx2[8], fy2[8], fha[8];
        #pragma unroll
        for (int q = 0; q < 8; ++q) {                    // uniform -> s_load
            float4 rc = rowc[rg + q];
            fx1[q] = rc.x; fy1[q] = rc.y; fx2[q] = rc.z; fy2[q] = rc.w;
            fha[q] = rowh[rg + q];
        }
        #pragma unroll
        for (int q = 0; q < 8; ++q) {
            float iw0 = fmaxf(fminf(fx2[q], c0c.z) - fmaxf(fx1[q], c0c.x), 0.0f);
            float ih0 = fmaxf(fminf(fy2[q], c0c.w) - fmaxf(fy1[q], c0c.y), 0.0f);
            float in0 = iw0 * ih0;
            bool p0 = in0 > fmaf(-0.5f, in0, fha[q] + h0);

            float iw1 = fmaxf(fminf(fx2[q], c1c.z) - fmaxf(fx1[q], c1c.x), 0.0f);
            float ih1 = fmaxf(fminf(fy2[q], c1c.w) - fmaxf(fy1[q], c1c.y), 0.0f);
            float in1 = iw1 * ih1;
            bool p1 = in1 > fmaf(-0.5f, in1, fha[q] + h1);

            u64 b0 = __ballot(p0);
            u64 b1 = __ballot(p1);
            if (lane == rg + q) { w0 = b0; w1 = b1; }
        }
    }

    ulonglong2 v; v.x = w0; v.y = w1;
    *(ulonglong2*)&mask[(base + rowbase + lane) * NMS_NW + wp * 2] = v;
}

// ---------------------------------------------------------------------------
// K3: one wave per batch, serial greedy scan. Suppression state: one u64 per
// lane (lane = 64-row window). Current window's word broadcast to scalar;
// kept rows OR their (double-buffered, prefetched) mask row into supp.
// Loads predicated on lane >= window: below-diagonal words are garbage and
// never consumed. Early exit at 256 keeps.
// ---------------------------------------------------------------------------
__global__ __launch_bounds__(64, 1) void nms_scan(
        const float* __restrict__ in, const u64* __restrict__ mask,
        const u32* __restrict__ sortedIdx, float* __restrict__ outp) {
    const int b = blockIdx.x, lane = threadIdx.x;
    const u64* M = mask + (size_t)b * NMS_N * NMS_NW;

    __shared__ int kept[ROIS];
    for (int r = lane; r < ROIS; r += 64) kept[r] = 0;   // safety fallback

    u64 supp = 0;
    int count = 0;
    u64 bufA[64], bufB[64];

    #pragma unroll
    for (int r = 0; r < 64; ++r) bufA[r] = M[(size_t)r * NMS_NW + lane];

#define PROCESS(BUF, W)                                                    \
    {                                                                      \
        u64 curwin = rdlane_u64(supp, (W));                                \
        _Pragma("unroll")                                                  \
        for (int r = 0; r < 64; ++r) {                                     \
            if (count < ROIS && !((curwin >> r) & 1ULL)) {                 \
                if (lane == 0) kept[count] = (W) * 64 + r;                 \
                supp |= BUF[r];                                            \
                curwin |= rdlane_u64(BUF[r], (W));                         \
                ++count;                                                   \
            }                                                              \
        }                                                                  \
    }

    for (int w = 0; w < 64 && count < ROIS; w += 2) {
        // prefetch window w+1 into B (skip never-consumed words lane < w+1)
        #pragma unroll
        for (int r = 0; r < 64; ++r)
            bufB[r] = (lane >= w + 1)
                          ? M[(size_t)((w + 1) * 64 + r) * NMS_NW + lane] : 0ULL;
        PROCESS(bufA, w);
        if (count >= ROIS) break;
        // prefetch window w+2 into A
        if (w + 2 < 64) {
            #pragma unroll
            for (int r = 0; r < 64; ++r)
                bufA[r] = (lane >= w + 2)
                              ? M[(size_t)((w + 2) * 64 + r) * NMS_NW + lane] : 0ULL;
        }
        PROCESS(bufB, w + 1);
    }
#undef PROCESS

    __syncthreads();
    for (int r = lane; r < ROIS; r += 64) {
        int pos = kept[r];
        int orig = (int)sortedIdx[(size_t)b * NMS_N + pos];
        const float* bp = in + ((size_t)b * NMS_N + orig) * 5;
        float4 o = make_float4(bp[1], bp[2], bp[3], bp[4]);
        ((float4*)outp)[(size_t)b * ROIS + r] = o;
    }
}

extern "C" void kernel_launch(void* const* d_in, const int* in_sizes, int n_in,
                              void* d_out, int out_size, void* d_ws, size_t ws_size,
                              hipStream_t stream) {
    const float* in = (const float*)d_in[0];
    float* out = (float*)d_out;
    char* ws = (char*)d_ws;

    u64* mask = (u64*)ws;                                          // 16 MB
    size_t off = (size_t)NMS_B * NMS_N * NMS_NW * sizeof(u64);
    u32* sortedIdx = (u32*)(ws + off); off += (size_t)NMS_B * NMS_N * 4;
    float4* crn = (float4*)(ws + off); off += (size_t)NMS_B * NMS_N * 16;
    float* ha = (float*)(ws + off);    off += (size_t)NMS_B * NMS_N * 4;

    nms_sort<<<NMS_B, 1024, 0, stream>>>(in, sortedIdx, crn, ha);
    nms_mask<<<dim3(264, NMS_B), 256, 0, stream>>>(crn, ha, mask);
    nms_scan<<<NMS_B, 64, 0, stream>>>(in, mask, sortedIdx, out);
}

// Round 4
// 148.435 us; speedup vs baseline: 1.4840x; 1.0360x over previous
//
#include <hip/hip_runtime.h>
#include <stdint.h>

#pragma clang fp contract(off)

#define NMS_B 8
#define NMS_N 4096
#define NMS_NW 64       // 64-bit words per suppression row
#define ROIS 256

typedef unsigned long long u64;
typedef unsigned int u32;

__device__ __forceinline__ u64 rdlane_u64(u64 v, int l) {
    u32 lo = (u32)__builtin_amdgcn_readlane((int)(u32)v, l);
    u32 hi = (u32)__builtin_amdgcn_readlane((int)(u32)(v >> 32), l);
    return ((u64)hi << 32) | lo;
}
__device__ __forceinline__ u64 rdfirst_u64(u64 v) {
    u32 lo = (u32)__builtin_amdgcn_readfirstlane((int)(u32)v);
    u32 hi = (u32)__builtin_amdgcn_readfirstlane((int)(u32)(v >> 32));
    return ((u64)hi << 32) | lo;
}
__device__ __forceinline__ int lds_slot(int e) { return e + (e >> 2); }  // 4-way max bank aliasing

// ---------------------------------------------------------------------------
// K1: per-batch stable descending sort by score. Register-blocked bitonic:
// each of 1024 threads owns 4 consecutive elements (key = (~score)<<32|idx).
// j<=2 in-register, j=4..128 via shfl_xor within the wave, j>=256 via LDS
// compare-swap chains. Epilogue writes sorted idx + corners (floor(w/2),
// exactly per reference) + HALF-areas (exact: areas are small even ints).
// ---------------------------------------------------------------------------
__global__ __launch_bounds__(1024) void nms_sort(
        const float* __restrict__ in, u32* __restrict__ sortedIdx,
        float4* __restrict__ crn, float* __restrict__ ha) {
    __shared__ u64 sm[5120];                  // slot(4095)=5118 -> 41 KB
    const int b = blockIdx.x, t = threadIdx.x;
    u64 key[4];

    #pragma unroll
    for (int r = 0; r < 4; ++r) {
        int e = 4 * t + r;
        float s = in[((size_t)b * NMS_N + e) * 5 + 0];
        key[r] = ((u64)(~__float_as_uint(s)) << 32) | (u32)e;
    }

    for (int k = 2; k <= NMS_N; k <<= 1) {
        int j = k >> 1;
        if (j >= 256) {                        // LDS chain for big strides
            #pragma unroll
            for (int r = 0; r < 4; ++r) sm[lds_slot(4 * t + r)] = key[r];
            __syncthreads();
            for (; j >= 256; j >>= 1) {
                for (int e = t; e < NMS_N; e += 1024) {
                    int p = e ^ j;
                    if (p > e) {
                        u64 a = sm[lds_slot(e)], c = sm[lds_slot(p)];
                        bool up = ((e & k) == 0);
                        if ((a > c) == up) { sm[lds_slot(e)] = c; sm[lds_slot(p)] = a; }
                    }
                }
                __syncthreads();
            }
            #pragma unroll
            for (int r = 0; r < 4; ++r) key[r] = sm[lds_slot(4 * t + r)];
        }
        for (; j >= 4; j >>= 1) {              // cross-thread via shfl_xor
            int d = j >> 2;
            #pragma unroll
            for (int r = 0; r < 4; ++r) {
                int e = 4 * t + r;
                u64 mine = key[r];
                u64 part = __shfl_xor(mine, d, 64);
                bool up = ((e & k) == 0);
                bool lower = ((e & j) == 0);
                u64 mn = (mine < part) ? mine : part;
                u64 mx = (mine < part) ? part : mine;
                key[r] = (up == lower) ? mn : mx;
            }
        }
        for (; j >= 1; j >>= 1) {              // j in {2,1}: in-thread
            #pragma unroll
            for (int r = 0; r < 4; ++r) {
                int pr = r | j;
                if (((r & j) == 0) && pr < 4) {
                    int e = 4 * t + r;
                    bool up = ((e & k) == 0);
                    u64 a = key[r], c = key[pr];
                    if ((a > c) == up) { key[r] = c; key[pr] = a; }
                }
            }
        }
    }

    #pragma unroll
    for (int r = 0; r < 4; ++r) {
        int e = 4 * t + r;
        u32 orig = (u32)key[r];
        const float* bp = in + ((size_t)b * NMS_N + orig) * 5;
        float x = bp[1], y = bp[2], w = bp[3], h = bp[4];
        float ws_ = floorf(w * 0.5f);
        float hs_ = floorf(h * 0.5f);
        float X1 = x - ws_, Y1 = y - hs_, X2 = x + ws_, Y2 = y + hs_;
        size_t g = (size_t)b * NMS_N + e;
        sortedIdx[g] = orig;
        crn[g] = make_float4(X1, Y1, X2, Y2);
        ha[g] = 0.5f * ((X2 - X1) * (Y2 - Y1));   // exact: area is a small int
    }
}

// ---------------------------------------------------------------------------
// K2: suppression bitmask, ballot orientation, EQUAL-WORK trapezoid grid.
// One wave = one unit = 64 rows x 128 cols. Units per word-pair wp:
// 2*(wp+1); cumulative = wp*(wp+1). 1056 units/batch, 4 waves/block.
// Each lane owns TWO columns (regs); rows are wave-uniform scalar loads;
// v_cmp/__ballot emits the mask word directly.
// Test inter > (hra+hca) - 0.5*inter  ==  inter/union > 0.5 bit-exactly.
// Below-diagonal words are never written NOR read by the scan.
// ---------------------------------------------------------------------------
__global__ __launch_bounds__(256) void nms_mask(
        const float4* __restrict__ crn, const float* __restrict__ ha,
        u64* __restrict__ mask) {
    const int b = blockIdx.y;
    const int u = blockIdx.x * 4 + (threadIdx.x >> 6);   // unit id, 0..1055
    const int lane = threadIdx.x & 63;

    // triangular decode: wp s.t. wp*(wp+1) <= u < (wp+1)*(wp+2)
    int wp = (int)sqrtf((float)u);
    while (wp * (wp + 1) > u) --wp;
    while ((wp + 1) * (wp + 2) <= u) ++wp;
    const int rowblk = u - wp * (wp + 1);                // 0..2*wp+1

    const size_t base = (size_t)b * NMS_N;
    const int c0 = wp * 128 + lane;
    float4 c0c = crn[base + c0];
    float4 c1c = crn[base + c0 + 64];
    float h0 = ha[base + c0];
    float h1 = ha[base + c0 + 64];

    const int rowbase = __builtin_amdgcn_readfirstlane(rowblk * 64);
    const float4* rowc = crn + base + rowbase;
    const float* rowh = ha + base + rowbase;

    u64 w0 = 0, w1 = 0;
    for (int rg = 0; rg < 64; rg += 8) {
        float fx1[8], fy1[8], fx2[8], fy2[8], fha[8];
        #pragma unroll
        for (int q = 0; q < 8; ++q) {                    // uniform -> s_load
            float4 rc = rowc[rg + q];
            fx1[q] = rc.x; fy1[q] = rc.y; fx2[q] = rc.z; fy2[q] = rc.w;
            fha[q] = rowh[rg + q];
        }
        #pragma unroll
        for (int q = 0; q < 8; ++q) {
            float iw0 = fmaxf(fminf(fx2[q], c0c.z) - fmaxf(fx1[q], c0c.x), 0.0f);
            float ih0 = fmaxf(fminf(fy2[q], c0c.w) - fmaxf(fy1[q], c0c.y), 0.0f);
            float in0 = iw0 * ih0;
            bool p0 = in0 > fmaf(-0.5f, in0, fha[q] + h0);

            float iw1 = fmaxf(fminf(fx2[q], c1c.z) - fmaxf(fx1[q], c1c.x), 0.0f);
            float ih1 = fmaxf(fminf(fy2[q], c1c.w) - fmaxf(fy1[q], c1c.y), 0.0f);
            float in1 = iw1 * ih1;
            bool p1 = in1 > fmaf(-0.5f, in1, fha[q] + h1);

            u64 b0 = __ballot(p0);
            u64 b1 = __ballot(p1);
            if (lane == rg + q) { w0 = b0; w1 = b1; }
        }
    }

    ulonglong2 v; v.x = w0; v.y = w1;
    *(ulonglong2*)&mask[(base + rowbase + lane) * NMS_NW + wp * 2] = v;
}

// ---------------------------------------------------------------------------
// K3 v2: one wave per batch, stateless-window greedy scan.
// Per window W (64 rows):
//   curwin = OR over all kept rows so far of their mask word W
//            (<=4 independent loads/lane over the kept list + shfl_xor
//             OR-butterfly -> wave-uniform, one memory latency)
//   diag   = prefetched: lane r holds mask word W of row 64W+r
//   serial SCALAR ctz loop: r = ctz(avail); keep row; avail &= ~(diag_r|1<<r)
//            -- suppressed rows cost zero iterations. Self-bit cleared
//            explicitly (zero-area boxes have IoU(i,i)=0 -> no self-bit).
// No per-lane suppression state, no register buffers -> no spills.
// ---------------------------------------------------------------------------
__global__ __launch_bounds__(64, 1) void nms_scan(
        const float* __restrict__ in, const u64* __restrict__ mask,
        const u32* __restrict__ sortedIdx, float* __restrict__ outp) {
    const int b = blockIdx.x, lane = threadIdx.x;
    const u64* M = mask + (size_t)b * NMS_N * NMS_NW;

    __shared__ int kept[ROIS];
    for (int r = lane; r < ROIS; r += 64) kept[r] = 0;   // safety fallback

    int count = 0;
    // diag for window 0: lane r holds word 0 of row r
    u64 diag = M[(size_t)lane * NMS_NW + 0];

    for (int W = 0; W < 64 && count < ROIS; ++W) {
        // prefetch next window's diagonal early (hide behind gather+scan)
        u64 nextdiag = 0;
        if (W + 1 < 64)
            nextdiag = M[(size_t)((W + 1) * 64 + lane) * NMS_NW + (W + 1)];

        // ---- curwin: OR of kept rows' word W ----
        u64 curwin = 0;
        if (count > 0) {
            const int cm1 = count - 1;
            u64 acc = 0;
            #pragma unroll
            for (int s = 0; s < 4; ++s) {                // 4 independent loads
                int j = lane + s * 64;
                int jj = j <= cm1 ? j : cm1;
                int pos = kept[jj];
                u64 v = M[(size_t)pos * NMS_NW + W];
                if (j <= cm1) acc |= v;
            }
            #pragma unroll
            for (int d2 = 1; d2 < 64; d2 <<= 1)          // OR-butterfly
                acc |= (u64)__shfl_xor((long long)acc, d2, 64);
            curwin = rdfirst_u64(acc);
        }

        // ---- serial scalar ctz-skip scan of this window ----
        u64 avail = ~curwin;
        while (avail != 0 && count < ROIS) {
            int r = __builtin_ctzll(avail);
            u64 d = rdlane_u64(diag, r);
            if (lane == 0) kept[count] = W * 64 + r;
            ++count;
            avail &= ~(d | (1ULL << r));
        }

        diag = nextdiag;
    }

    __syncthreads();
    for (int r = lane; r < ROIS; r += 64) {
        int pos = kept[r];
        int orig = (int)sortedIdx[(size_t)b * NMS_N + pos];
        const float* bp = in + ((size_t)b * NMS_N + orig) * 5;
        float4 o = make_float4(bp[1], bp[2], bp[3], bp[4]);
        ((float4*)outp)[(size_t)b * ROIS + r] = o;
    }
}

extern "C" void kernel_launch(void* const* d_in, const int* in_sizes, int n_in,
                              void* d_out, int out_size, void* d_ws, size_t ws_size,
                              hipStream_t stream) {
    const float* in = (const float*)d_in[0];
    float* out = (float*)d_out;
    char* ws = (char*)d_ws;

    u64* mask = (u64*)ws;                                          // 16 MB
    size_t off = (size_t)NMS_B * NMS_N * NMS_NW * sizeof(u64);
    u32* sortedIdx = (u32*)(ws + off); off += (size_t)NMS_B * NMS_N * 4;
    float4* crn = (float4*)(ws + off); off += (size_t)NMS_B * NMS_N * 16;
    float* ha = (float*)(ws + off);    off += (size_t)NMS_B * NMS_N * 4;

    nms_sort<<<NMS_B, 1024, 0, stream>>>(in, sortedIdx, crn, ha);
    nms_mask<<<dim3(264, NMS_B), 256, 0, stream>>>(crn, ha, mask);
    nms_scan<<<NMS_B, 64, 0, stream>>>(in, mask, sortedIdx, out);
}